// Round 3
// baseline (2752.416 us; speedup 1.0000x reference)
//
#include <hip/hip_runtime.h>
#include <hip/hip_bf16.h>

#define BB 512
#define SS 2048
#define VV 29
#define HH 128

// h LDS layout: quarter q (32 floats) starts at float-offset q*40 (stride-40 pad).
// A wave's 4 quarter-streams then hit banks {8q+4c} -- pairwise disjoint -> no conflicts.
#define HPOS(j) (((j) >> 5) * 40 + ((j) & 31))

__device__ __forceinline__ float fast_tanh(float z) {
    // tanh(z) = sign(z) * (1 - 2e/(1+e)),  e = exp(-2|z|)
    float az = fabsf(z);
    float e  = __expf(-2.0f * az);
    float r  = 1.0f - 2.0f * e * __builtin_amdgcn_rcpf(1.0f + e);
    return copysignf(r, z);
}

// One block per batch row, 512 threads.
// Encoder: output i = tid>>2 (0..127), K-quarter q = tid&3.
//   - h-dot: 32 FMAs over h[q*32..q*32+32) (broadcast LDS reads, conflict-free layout)
//   - x-dot: ~8 FMAs over x-quarter {0..7 | 8..15 | 16..22 | 23..28}
//   - reduction: __shfl_xor(1) + __shfl_xor(2)  (in-wave, no LDS, no barrier)
//   - ONE __syncthreads per step (h publish + x-ring handoff)
//   - x prefetched 8..16 steps ahead via a 2-half LDS ring (1 coalesced load / 8 steps)
// Decoder: single wave, h in lanes, __shfl broadcast, zero barriers (round-2 proven).
__global__ __launch_bounds__(512) void rnn_fused(
    const float* __restrict__ x,      // (B,S,V)
    const float* __restrict__ We_ih,  // (H,V)
    const float* __restrict__ We_hh,  // (H,H)
    const float* __restrict__ be_ih,  // (H)
    const float* __restrict__ be_hh,  // (H)
    const float* __restrict__ Wd_ih,  // (V,H)
    const float* __restrict__ Wd_hh,  // (V,V)
    const float* __restrict__ bd_ih,  // (V)
    const float* __restrict__ bd_hh,  // (V)
    float* __restrict__ out)          // (B,S,V)
{
    const int b   = blockIdx.x;
    const int tid = threadIdx.x;
    const int i   = tid >> 2;   // output index 0..127
    const int q   = tid & 3;    // K-quarter

    __shared__ float hbuf[2][160];      // padded quarters (stride 40)
    __shared__ float xring[2][240];     // 2 halves x 8 steps x 29 floats (+pad)

    // ---- weights to registers ----
    float w[32];
    {
        const float* wrow = We_hh + i * HH + q * 32;
        #pragma unroll
        for (int j = 0; j < 32; ++j) w[j] = wrow[j];
    }

    // x-quarter split: 8 + 8 + 7 + 6 = 29
    const int xoff = (q == 0) ? 0 : (q == 1) ? 8 : (q == 2) ? 16 : 23;
    const int xn   = (q == 0) ? 8 : (q == 1) ? 8 : (q == 2) ? 7 : 6;
    float wx[8];
    #pragma unroll
    for (int j = 0; j < 8; ++j)
        wx[j] = (j < xn) ? We_ih[i * VV + xoff + j] : 0.0f;

    const float bias = (q == 0) ? (be_ih[i] + be_hh[i]) : 0.0f;

    const float* xb = x + (size_t)b * SS * VV;

    // ---- init: h=0, prime x-ring ----
    if (tid < 160) { hbuf[0][tid] = 0.0f; hbuf[1][tid] = 0.0f; }
    float xv = 0.0f;
    if (tid < 240) {
        xring[0][tid] = (tid < 232) ? xb[tid] : 0.0f;    // steps 0..7
        xring[1][tid] = 0.0f;                             // pads (and placeholder)
    }
    if (tid < 232) xv = xb[232 + tid];                    // steps 8..15 in flight
    __syncthreads();

    float* hcur = hbuf[0];
    float* hnxt = hbuf[1];
    int half = 0;

    // ---- encoder scan: ONE barrier per step ----
    for (int t = 0; t < SS; ++t) {
        const int s = t & 7;

        // h-dot over this thread's K-quarter (broadcast reads, conflict-free)
        const float* hq = hcur + q * 40;
        float a0 = 0.f, a1 = 0.f, a2 = 0.f, a3 = 0.f;
        #pragma unroll
        for (int j = 0; j < 32; j += 4) {
            a0 += w[j + 0] * hq[j + 0];
            a1 += w[j + 1] * hq[j + 1];
            a2 += w[j + 2] * hq[j + 2];
            a3 += w[j + 3] * hq[j + 3];
        }
        // x-dot from the ring
        const float* xs = &xring[half][s * VV + xoff];
        float accx = bias;
        #pragma unroll
        for (int j = 0; j < 8; ++j) accx += wx[j] * xs[j];

        float p = (a0 + a1) + (a2 + a3) + accx;
        // in-wave split-K reduction across the 4 quarter lanes
        p += __shfl_xor(p, 1, 64);
        p += __shfl_xor(p, 2, 64);

        float hn = fast_tanh(p);
        if (q == 0) hnxt[HPOS(i)] = hn;

        if (s == 7) {
            // hand off the in-flight 8 steps to the other ring half,
            // then issue loads for 8 steps further out.
            if (tid < 232) xring[half ^ 1][tid] = xv;
            int base = (t + 9) * VV + tid;
            if (tid < 232) xv = (base < SS * VV) ? xb[base] : 0.0f;
            half ^= 1;
        }
        __syncthreads();

        float* tmp = hcur; hcur = hnxt; hnxt = tmp;
    }
    // SS even -> encoded vector is in hbuf[0] (== hcur)

    // ---- decoder: single wave (threads 0..63), no barriers ----
    if (tid >= 64) return;
    const int lane = tid;
    const int r = (lane < VV) ? lane : (VV - 1);   // lanes >=29 mirror row 28

    float di = bd_ih[r] + bd_hh[r];
    {
        const float* wdi = Wd_ih + r * HH;
        float d0 = 0.f, d1 = 0.f, d2 = 0.f, d3 = 0.f;
        #pragma unroll
        for (int j = 0; j < HH; j += 4) {
            d0 += wdi[j + 0] * hbuf[0][HPOS(j + 0)];
            d1 += wdi[j + 1] * hbuf[0][HPOS(j + 1)];
            d2 += wdi[j + 2] * hbuf[0][HPOS(j + 2)];
            d3 += wdi[j + 3] * hbuf[0][HPOS(j + 3)];
        }
        di += (d0 + d1) + (d2 + d3);
    }

    float wd[VV];
    {
        const float* wdr = Wd_hh + r * VV;
        #pragma unroll
        for (int j = 0; j < VV; ++j) wd[j] = wdr[j];
    }

    float hd = 0.0f;
    float* ob = out + (size_t)b * SS * VV;
    for (int t = 0; t < SS; ++t) {
        float a0 = di, a1 = 0.f, a2 = 0.f, a3 = 0.f;
        #pragma unroll
        for (int j = 0; j < VV; j += 4) {
            a0 += wd[j] * __shfl(hd, j, 64);
            if (j + 1 < VV) a1 += wd[j + 1] * __shfl(hd, j + 1, 64);
            if (j + 2 < VV) a2 += wd[j + 2] * __shfl(hd, j + 2, 64);
            if (j + 3 < VV) a3 += wd[j + 3] * __shfl(hd, j + 3, 64);
        }
        float hn = fast_tanh((a0 + a1) + (a2 + a3));
        hd = hn;
        if (lane < VV) ob[t * VV + lane] = hn;
    }
}

extern "C" void kernel_launch(void* const* d_in, const int* in_sizes, int n_in,
                              void* d_out, int out_size, void* d_ws, size_t ws_size,
                              hipStream_t stream) {
    const float* x     = (const float*)d_in[0];
    const float* We_ih = (const float*)d_in[1];
    const float* We_hh = (const float*)d_in[2];
    const float* be_ih = (const float*)d_in[3];
    const float* be_hh = (const float*)d_in[4];
    const float* Wd_ih = (const float*)d_in[5];
    const float* Wd_hh = (const float*)d_in[6];
    const float* bd_ih = (const float*)d_in[7];
    const float* bd_hh = (const float*)d_in[8];
    float* out = (float*)d_out;

    rnn_fused<<<dim3(BB), dim3(512), 0, stream>>>(
        x, We_ih, We_hh, be_ih, be_hh, Wd_ih, Wd_hh, bd_ih, bd_hh, out);
}

// Round 4
// 2700.309 us; speedup vs baseline: 1.0193x; 1.0193x over previous
//
#include <hip/hip_runtime.h>
#include <hip/hip_bf16.h>

#define SS 2048
#define VV 29
#define HH 128
#define ROWS 16
#define NBLK 32           // 512 / 16 rows

typedef _Float16 h8 __attribute__((ext_vector_type(8)));
typedef float    f4 __attribute__((ext_vector_type(4)));

// ---------------- LDS map (bytes) ----------------
// H limb buffers (double-buffered): (p*2+limb)*4352 + n*272 + k*2   (n<16, k<128)
//   KPITCH_H = 272 = 16*17 (odd 16B-granule pitch -> conflict-free b128 frag reads)
// X slot ring: XBASE + limb*20480 + slot*1280 + n*80 + v*2          (slot<16, v<32)
//   KPITCH_X = 80 = 16*5 (odd granule pitch)
#define HBUF(p, limb) (((p) * 2 + (limb)) * 4352)
#define XBASE 17408
#define XLIMB 20480
#define LDS_BYTES 58368
#define NX (ROWS * 8 * VV)   // elems per 8-step x refill = 3712

__device__ __forceinline__ float fast_tanh(float z) {
    // identical to rounds 1-3 (part of the verified 0.0039 error budget)
    float az = fabsf(z);
    float e  = __expf(-2.0f * az);
    float r  = 1.0f - 2.0f * e * __builtin_amdgcn_rcpf(1.0f + e);
    return copysignf(r, z);
}

__device__ __forceinline__ unsigned long long pack4h(const _Float16* f) {
    union { _Float16 h[4]; unsigned long long u; } u;
    u.h[0] = f[0]; u.h[1] = f[1]; u.h[2] = f[2]; u.h[3] = f[3];
    return u.u;
}

// x refill: loads for steps T0..T0+7 were issued into xr[] one period ago;
// XSTORE converts+writes them to the ring, XLOAD issues the next period's loads.
#define XLOAD(T0)                                                            \
    _Pragma("unroll")                                                        \
    for (int ii = 0; ii < 15; ++ii) {                                        \
        int e = tid + ii * 256;                                              \
        if (e < NX) {                                                        \
            int row = e / 232; int rem = e - row * 232;                      \
            int s = rem / 29;  int v = rem - s * 29;                         \
            int T = (T0) + s;  if (T > SS - 1) T = SS - 1;                   \
            xr[ii] = x[(size_t)(b0 + row) * (SS * VV) + T * VV + v];         \
        }                                                                    \
    }

#define XSTORE(T0)                                                           \
    _Pragma("unroll")                                                        \
    for (int ii = 0; ii < 15; ++ii) {                                        \
        int e = tid + ii * 256;                                              \
        if (e < NX) {                                                        \
            int row = e / 232; int rem = e - row * 232;                      \
            int s = rem / 29;  int v = rem - s * 29;                         \
            int slot = ((T0) + s) & 15;                                      \
            int base = XBASE + slot * 1280 + row * 80 + v * 2;               \
            _Float16 l0 = (_Float16)xr[ii];                                  \
            _Float16 l1 = (_Float16)(xr[ii] - (float)l0);                    \
            *(_Float16*)(lds + base)          = l0;                          \
            *(_Float16*)(lds + base + XLIMB)  = l1;                          \
        }                                                                    \
    }

// Encoder: one block = 16 batch rows, 256 threads (4 waves).
// Y(128x16) = [We_hh | We_ih](128x160) . [h ; x](160x16) via mfma 16x16x32 f16,
// double-limb fp16 (W0H0 + W0H1 + W1H0) for ~2^-22 per-step accuracy.
// Wave w owns M-tiles {2w, 2w+1}; full K per wave -> no cross-wave reduction.
// ONE __syncthreads per step. Writes final h (fp32) into row's own out region.
__global__ __launch_bounds__(256) void enc_kernel(
    const float* __restrict__ x,
    const float* __restrict__ We_ih,
    const float* __restrict__ We_hh,
    const float* __restrict__ be_ih,
    const float* __restrict__ be_hh,
    float* __restrict__ out)
{
    __shared__ uint4 ldsmem[LDS_BYTES / 16];
    char* lds = (char*)ldsmem;

    const int tid  = threadIdx.x;
    const int lane = tid & 63;
    const int w    = tid >> 6;      // wave id 0..3
    const int n    = lane & 15;     // frag 16-index: batch row (B/C), m-low (A)
    const int q    = lane >> 4;     // quad
    const int b0   = blockIdx.x * ROWS;

    // ---- A fragments (weights) -> registers, once ----
    // A[m][k]: m = lane&15 (+16*tile), k = quad*8 + j (+32*kt)   [guide §3, m120]
    h8 A[2][5][2];
    #pragma unroll
    for (int tt = 0; tt < 2; ++tt) {
        const int m = (w * 2 + tt) * 16 + n;
        #pragma unroll
        for (int kt = 0; kt < 5; ++kt) {
            #pragma unroll
            for (int j = 0; j < 8; ++j) {
                int k = kt * 32 + q * 8 + j;
                float v;
                if (k < HH)            v = We_hh[m * HH + k];
                else if (k - HH < VV)  v = We_ih[m * VV + (k - HH)];
                else                   v = 0.0f;
                _Float16 l0 = (_Float16)v;
                A[tt][kt][0][j] = l0;
                A[tt][kt][1][j] = (_Float16)(v - (float)l0);
            }
        }
    }
    float bias[2][4];
    #pragma unroll
    for (int tt = 0; tt < 2; ++tt)
        #pragma unroll
        for (int r = 0; r < 4; ++r) {
            int m = (w * 2 + tt) * 16 + q * 4 + r;
            bias[tt][r] = be_ih[m] + be_hh[m];
        }

    // ---- zero LDS (h=0 at t=0; x pad lanes stay 0) ----
    for (int o = tid; o < LDS_BYTES / 16; o += 256) {
        uint4 z; z.x = z.y = z.z = z.w = 0u;
        ldsmem[o] = z;
    }
    __syncthreads();

    // ---- prime x ring: steps 0..15 in LDS, 16..23 in flight in xr ----
    float xr[15];
    XLOAD(0);  XSTORE(0);
    XLOAD(8);  XSTORE(8);
    XLOAD(16);
    __syncthreads();

    int p = 0;
    for (int t = 0; t < SS; ++t) {
        // ---- B fragments: B[k][n], n = lane&15, k = quad*8+j (+32*kt) ----
        const int hb = HBUF(p, 0) + n * 272 + q * 16;
        h8 bh0[4], bh1[4];
        #pragma unroll
        for (int kt = 0; kt < 4; ++kt) {
            bh0[kt] = *(const h8*)(lds + hb + kt * 64);
            bh1[kt] = *(const h8*)(lds + hb + 4352 + kt * 64);
        }
        const int xoff = XBASE + (t & 15) * 1280 + n * 80 + q * 16;
        h8 bx0 = *(const h8*)(lds + xoff);
        h8 bx1 = *(const h8*)(lds + xoff + XLIMB);

        #pragma unroll
        for (int tt = 0; tt < 2; ++tt) {
            f4 C0 = {0.f, 0.f, 0.f, 0.f};
            f4 C1 = {0.f, 0.f, 0.f, 0.f};
            f4 C2 = {0.f, 0.f, 0.f, 0.f};
            #pragma unroll
            for (int kt = 0; kt < 4; ++kt) {
                C0 = __builtin_amdgcn_mfma_f32_16x16x32_f16(A[tt][kt][0], bh0[kt], C0, 0, 0, 0);
                C1 = __builtin_amdgcn_mfma_f32_16x16x32_f16(A[tt][kt][0], bh1[kt], C1, 0, 0, 0);
                C2 = __builtin_amdgcn_mfma_f32_16x16x32_f16(A[tt][kt][1], bh0[kt], C2, 0, 0, 0);
            }
            C0 = __builtin_amdgcn_mfma_f32_16x16x32_f16(A[tt][4][0], bx0, C0, 0, 0, 0);
            C1 = __builtin_amdgcn_mfma_f32_16x16x32_f16(A[tt][4][0], bx1, C1, 0, 0, 0);
            C2 = __builtin_amdgcn_mfma_f32_16x16x32_f16(A[tt][4][1], bx0, C2, 0, 0, 0);

            // ---- epilogue: tanh, split to fp16 limbs, publish to other buffer ----
            // C/D layout: col = lane&15 = n (batch row), row = quad*4 + reg = m
            const int m0 = (w * 2 + tt) * 16 + q * 4;
            float hv[4];
            _Float16 l0[4], l1[4];
            #pragma unroll
            for (int r = 0; r < 4; ++r) {
                float y = C0[r] + C1[r] + C2[r] + bias[tt][r];
                hv[r] = fast_tanh(y);
                l0[r] = (_Float16)hv[r];
                l1[r] = (_Float16)(hv[r] - (float)l0[r]);
            }
            const int wb = HBUF(p ^ 1, 0) + n * 272 + m0 * 2;
            *(unsigned long long*)(lds + wb)        = pack4h(l0);
            *(unsigned long long*)(lds + wb + 4352) = pack4h(l1);

            if (t == SS - 1) {
                // encoded vector (fp32) -> row's own output region (decoder
                // reads it before overwriting)
                f4 hq = {hv[0], hv[1], hv[2], hv[3]};
                *(f4*)(out + (size_t)(b0 + n) * (SS * VV) + m0) = hq;
            }
        }

        if ((t & 7) == 0 && t) { XSTORE(t + 8); XLOAD(t + 16); }

        __syncthreads();
        p ^= 1;
    }
}

// Decoder: round-2-proven single-wave shfl recurrence, one block per batch row.
__global__ __launch_bounds__(64) void dec_kernel(
    const float* __restrict__ Wd_ih,  // (V,H)
    const float* __restrict__ Wd_hh,  // (V,V)
    const float* __restrict__ bd_ih,  // (V)
    const float* __restrict__ bd_hh,  // (V)
    float* __restrict__ out)          // (B,S,V); first 128 floats of each row = encoded
{
    const int row  = blockIdx.x;
    const int lane = threadIdx.x;
    float* orow = out + (size_t)row * (SS * VV);

    __shared__ float enc[HH];
    enc[lane]      = orow[lane];
    enc[lane + 64] = orow[lane + 64];
    __syncthreads();

    const int r = (lane < VV) ? lane : (VV - 1);   // lanes >=29 mirror row 28

    float di = bd_ih[r] + bd_hh[r];
    {
        const float* wdi = Wd_ih + r * HH;
        float d0 = 0.f, d1 = 0.f, d2 = 0.f, d3 = 0.f;
        #pragma unroll
        for (int j = 0; j < HH; j += 4) {
            d0 += wdi[j + 0] * enc[j + 0];
            d1 += wdi[j + 1] * enc[j + 1];
            d2 += wdi[j + 2] * enc[j + 2];
            d3 += wdi[j + 3] * enc[j + 3];
        }
        di += (d0 + d1) + (d2 + d3);
    }

    float wd[VV];
    {
        const float* wdr = Wd_hh + r * VV;
        #pragma unroll
        for (int j = 0; j < VV; ++j) wd[j] = wdr[j];
    }

    float hd = 0.0f;
    for (int t = 0; t < SS; ++t) {
        float a0 = di, a1 = 0.f, a2 = 0.f, a3 = 0.f;
        #pragma unroll
        for (int j = 0; j < VV; j += 4) {
            a0 += wd[j] * __shfl(hd, j, 64);
            if (j + 1 < VV) a1 += wd[j + 1] * __shfl(hd, j + 1, 64);
            if (j + 2 < VV) a2 += wd[j + 2] * __shfl(hd, j + 2, 64);
            if (j + 3 < VV) a3 += wd[j + 3] * __shfl(hd, j + 3, 64);
        }
        float hn = fast_tanh((a0 + a1) + (a2 + a3));
        hd = hn;
        if (lane < VV) orow[t * VV + lane] = hn;
    }
}

extern "C" void kernel_launch(void* const* d_in, const int* in_sizes, int n_in,
                              void* d_out, int out_size, void* d_ws, size_t ws_size,
                              hipStream_t stream) {
    const float* x     = (const float*)d_in[0];
    const float* We_ih = (const float*)d_in[1];
    const float* We_hh = (const float*)d_in[2];
    const float* be_ih = (const float*)d_in[3];
    const float* be_hh = (const float*)d_in[4];
    const float* Wd_ih = (const float*)d_in[5];
    const float* Wd_hh = (const float*)d_in[6];
    const float* bd_ih = (const float*)d_in[7];
    const float* bd_hh = (const float*)d_in[8];
    float* out = (float*)d_out;

    enc_kernel<<<dim3(NBLK), dim3(256), 0, stream>>>(
        x, We_ih, We_hh, be_ih, be_hh, out);
    dec_kernel<<<dim3(512), dim3(64), 0, stream>>>(
        Wd_ih, Wd_hh, bd_ih, bd_hh, out);
}